// Round 1
// baseline (53.669 us; speedup 1.0000x reference)
//
#include <hip/hip_runtime.h>

// Batched Tacrolimus PK derivative: out[i, :] = f(state[i, :], params[i])
// Memory-bound streaming kernel. 44 B in + 24 B out per row.

__global__ __launch_bounds__(256) void TacrolimusPK_kernel(
    const float* __restrict__ state,  // [n, 6]
    const float* __restrict__ Ktr,    // [n]
    const float* __restrict__ CL,     // [n]
    const float* __restrict__ Q,      // [n]
    const float* __restrict__ Vc,     // [n]
    const float* __restrict__ Vp,     // [n]
    float* __restrict__ out,          // [n, 6]
    int n)
{
    const int stride = gridDim.x * blockDim.x;
    for (int i = blockIdx.x * blockDim.x + threadIdx.x; i < n; i += stride) {
        const float2* sp = reinterpret_cast<const float2*>(state + 6ll * i);
        float2 s01 = sp[0];   // A_depot, A_g1
        float2 s23 = sp[1];   // A_g2,   A_g3
        float2 s45 = sp[2];   // A_c,    A_p

        float ktr = Ktr[i];
        float cl  = CL[i];
        float q   = Q[i];
        float vc  = Vc[i];
        float vp  = Vp[i];

        float rvc    = 1.0f / vc;
        float k_elim = cl * rvc;
        float k12    = q * rvc;
        float k21    = q / vp;

        float d0 = -ktr * s01.x;
        float d1 = ktr * (s01.x - s01.y);
        float d2 = ktr * (s01.y - s23.x);
        float d3 = ktr * (s23.x - s23.y);
        float d4 = ktr * s23.y - (k_elim + k12) * s45.x + k21 * s45.y;
        float d5 = k12 * s45.x - k21 * s45.y;

        float2* op = reinterpret_cast<float2*>(out + 6ll * i);
        op[0] = make_float2(d0, d1);
        op[1] = make_float2(d2, d3);
        op[2] = make_float2(d4, d5);
    }
}

extern "C" void kernel_launch(void* const* d_in, const int* in_sizes, int n_in,
                              void* d_out, int out_size, void* d_ws, size_t ws_size,
                              hipStream_t stream) {
    // setup_inputs order: t(0), state(1), Ktr(2), CL(3), Q(4), Vc(5), Vp(6)
    const float* state = (const float*)d_in[1];
    const float* Ktr   = (const float*)d_in[2];
    const float* CL    = (const float*)d_in[3];
    const float* Q     = (const float*)d_in[4];
    const float* Vc    = (const float*)d_in[5];
    const float* Vp    = (const float*)d_in[6];
    float* out = (float*)d_out;

    const int n = in_sizes[2];  // B
    const int block = 256;
    int blocks_needed = (n + block - 1) / block;
    int grid = blocks_needed < 2048 ? blocks_needed : 2048;  // grid-stride cap (G11)
    TacrolimusPK_kernel<<<grid, block, 0, stream>>>(state, Ktr, CL, Q, Vc, Vp, out, n);
}